// Round 12
// baseline (7032.088 us; speedup 1.0000x reference)
//
#include <hip/hip_runtime.h>
#include <math.h>

// Problem constants
#define HH   300
#define H3   900
#define MMOL 256
#define LATM 128
#define AA   32769        // 1 + 256*128
#define NBB  6
#define BBND 131073       // 1 + 4*256*128
#define AFD  133
#define BFD  147
#define MLR  (MMOL * LATM)   // 32768

static __device__ __forceinline__ float sigm(float x) { return 1.0f / (1.0f + expf(-x)); }

// ---------------------------------------------------------------------------
// Tiled fp32 GEMM, 128x64 tile, BK=16, 8x4 microtile, 256 threads.
// TRUE double-buffered LDS: one barrier per K-iteration (iter i reads buf[i&1],
// writes buf[(i+1)&1]; single end-of-iter barrier orders both).
// ---------------------------------------------------------------------------
template<bool RELU, bool BIAS, bool ACCUM>
__global__ __launch_bounds__(256)
void gemm_big(const float* __restrict__ X, int ldx, const float* __restrict__ W, int ldw,
              const float* __restrict__ Bias, float* __restrict__ C,
              int rows, int N, int K)
{
    __shared__ float Xs[2][16][132];
    __shared__ float Ws[2][16][68];
    const int row0 = blockIdx.x * 128;
    const int col0 = blockIdx.y * 64;
    const int tid  = threadIdx.x;
    const int tm   = (tid >> 4) * 8;
    const int tn   = (tid & 15) * 4;
    const bool xv  = ((ldx & 3) == 0);
    const bool wv  = ((ldw & 3) == 0);

    float px[2][4], pw[4];

    auto loadTile = [&](int k0) {
        const int rem = K - k0;
#pragma unroll
        for (int l = 0; l < 2; ++l) {
            int s = tid + l * 256;
            int r = s >> 2, kq = (s & 3) * 4;
            int gr = row0 + r;
            float v0 = 0, v1 = 0, v2 = 0, v3 = 0;
            if (gr < rows) {
                const float* xp = X + (long)gr * ldx + k0 + kq;
                if (xv && rem >= 16) {
                    float4 t4 = *(const float4*)xp;
                    v0 = t4.x; v1 = t4.y; v2 = t4.z; v3 = t4.w;
                } else {
                    if (kq + 0 < rem) v0 = xp[0];
                    if (kq + 1 < rem) v1 = xp[1];
                    if (kq + 2 < rem) v2 = xp[2];
                    if (kq + 3 < rem) v3 = xp[3];
                }
            }
            px[l][0] = v0; px[l][1] = v1; px[l][2] = v2; px[l][3] = v3;
        }
        {
            int r = tid >> 2, kq = (tid & 3) * 4;
            int gc = col0 + r;
            float v0 = 0, v1 = 0, v2 = 0, v3 = 0;
            if (gc < N) {
                const float* wp = W + (long)gc * ldw + k0 + kq;
                if (wv && rem >= 16) {
                    float4 t4 = *(const float4*)wp;
                    v0 = t4.x; v1 = t4.y; v2 = t4.z; v3 = t4.w;
                } else {
                    if (kq + 0 < rem) v0 = wp[0];
                    if (kq + 1 < rem) v1 = wp[1];
                    if (kq + 2 < rem) v2 = wp[2];
                    if (kq + 3 < rem) v3 = wp[3];
                }
            }
            pw[0] = v0; pw[1] = v1; pw[2] = v2; pw[3] = v3;
        }
    };
    auto commitTile = [&](int buf) {
#pragma unroll
        for (int l = 0; l < 2; ++l) {
            int s = tid + l * 256;
            int r = s >> 2, kq = (s & 3) * 4;
            Xs[buf][kq + 0][r] = px[l][0]; Xs[buf][kq + 1][r] = px[l][1];
            Xs[buf][kq + 2][r] = px[l][2]; Xs[buf][kq + 3][r] = px[l][3];
        }
        {
            int r = tid >> 2, kq = (tid & 3) * 4;
            Ws[buf][kq + 0][r] = pw[0]; Ws[buf][kq + 1][r] = pw[1];
            Ws[buf][kq + 2][r] = pw[2]; Ws[buf][kq + 3][r] = pw[3];
        }
    };

    float acc[8][4];
#pragma unroll
    for (int i = 0; i < 8; ++i)
#pragma unroll
        for (int j = 0; j < 4; ++j) acc[i][j] = 0.0f;

    loadTile(0);
    commitTile(0);
    __syncthreads();

    int cur = 0;
    for (int k0 = 0; k0 < K; k0 += 16) {
        const bool more = (k0 + 16 < K);
        if (more) loadTile(k0 + 16);          // global->regs, flies under compute
#pragma unroll
        for (int kk = 0; kk < 16; ++kk) {
            float4 xa = *(const float4*)&Xs[cur][kk][tm];
            float4 xb = *(const float4*)&Xs[cur][kk][tm + 4];
            float4 wq = *(const float4*)&Ws[cur][kk][tn];
            float xr[8] = {xa.x, xa.y, xa.z, xa.w, xb.x, xb.y, xb.z, xb.w};
            float wr[4] = {wq.x, wq.y, wq.z, wq.w};
#pragma unroll
            for (int i = 0; i < 8; ++i)
#pragma unroll
                for (int j = 0; j < 4; ++j)
                    acc[i][j] += xr[i] * wr[j];
        }
        if (more) commitTile(cur ^ 1);        // regs->other LDS buffer
        __syncthreads();                      // single barrier per iteration
        cur ^= 1;
    }

#pragma unroll
    for (int i = 0; i < 8; ++i) {
        int gr = row0 + tm + i;
        if (gr >= rows) continue;
#pragma unroll
        for (int j = 0; j < 4; ++j) {
            int gc = col0 + tn + j;
            if (gc >= N) continue;
            float v = acc[i][j];
            if (BIAS)  v += Bias[gc];
            if (ACCUM) v += C[(long)gr * N + gc];
            if (RELU)  v = fmaxf(v, 0.0f);
            C[(long)gr * N + gc] = v;
        }
    }
}

// transposeQ: Whh[900][300] -> WQ[(k/4)][n][4]  (float4-loadable per gate n)
__global__ void transposeQ(const float* __restrict__ in, float* __restrict__ out)
{
    long idx = (long)blockIdx.x * blockDim.x + threadIdx.x;
    if (idx >= 270000) return;
    int n = (int)(idx / 300), k = (int)(idx - (long)n * 300);
    out[(long)(k >> 2) * 3600 + n * 4 + (k & 3)] = in[idx];
}

// ---------------------------------------------------------------------------
// vw_hi_gemm: in-place staged GEMM (proven round-10 win, unchanged).
//   P[r, 0:150) = (P[r, 0:300) @ W^T)[:, 150:300)
// ---------------------------------------------------------------------------
__global__ __launch_bounds__(256)
void vw_hi_gemm(float* __restrict__ P, const float* __restrict__ W, int rows)
{
    __shared__ float Xs[16][132];
    __shared__ float Ws[16][192];
    const int row0 = blockIdx.x * 128;
    const int tid  = threadIdx.x;
    const int tm   = (tid >> 4) * 8;
    const int tn   = (tid & 15) * 4;

    float acc[8][12];
#pragma unroll
    for (int i = 0; i < 8; ++i)
#pragma unroll
        for (int j = 0; j < 12; ++j) acc[i][j] = 0.0f;

    for (int k0 = 0; k0 < 300; k0 += 16) {
        const int rem = 300 - k0;
#pragma unroll
        for (int l = 0; l < 2; ++l) {
            int s = tid + l * 256;
            int r = s >> 2, kq = (s & 3) * 4;
            int gr = row0 + r;
            float v0 = 0, v1 = 0, v2 = 0, v3 = 0;
            if (gr < rows) {
                const float* xp = P + (long)gr * 300 + k0 + kq;
                if (rem >= 16) {
                    float4 t4 = *(const float4*)xp;
                    v0 = t4.x; v1 = t4.y; v2 = t4.z; v3 = t4.w;
                } else {
                    if (kq + 0 < rem) v0 = xp[0];
                    if (kq + 1 < rem) v1 = xp[1];
                    if (kq + 2 < rem) v2 = xp[2];
                    if (kq + 3 < rem) v3 = xp[3];
                }
            }
            Xs[kq + 0][r] = v0; Xs[kq + 1][r] = v1;
            Xs[kq + 2][r] = v2; Xs[kq + 3][r] = v3;
        }
        for (int s = tid; s < 600; s += 256) {
            int r = s >> 2, kq = (s & 3) * 4;
            const float* wp = W + (long)(150 + r) * 300 + k0 + kq;
            float v0 = 0, v1 = 0, v2 = 0, v3 = 0;
            if (rem >= 16) {
                float4 t4 = *(const float4*)wp;
                v0 = t4.x; v1 = t4.y; v2 = t4.z; v3 = t4.w;
            } else {
                if (kq + 0 < rem) v0 = wp[0];
                if (kq + 1 < rem) v1 = wp[1];
                if (kq + 2 < rem) v2 = wp[2];
                if (kq + 3 < rem) v3 = wp[3];
            }
            Ws[kq + 0][r] = v0; Ws[kq + 1][r] = v1;
            Ws[kq + 2][r] = v2; Ws[kq + 3][r] = v3;
        }
        __syncthreads();
#pragma unroll
        for (int kk = 0; kk < 16; ++kk) {
            float4 xa = *(const float4*)&Xs[kk][tm];
            float4 xb = *(const float4*)&Xs[kk][tm + 4];
            float4 w0 = *(const float4*)&Ws[kk][tn];
            float4 w1 = *(const float4*)&Ws[kk][tn + 64];
            float4 w2 = *(const float4*)&Ws[kk][tn + 128];
            float xr[8] = {xa.x, xa.y, xa.z, xa.w, xb.x, xb.y, xb.z, xb.w};
            float wr[12] = {w0.x, w0.y, w0.z, w0.w, w1.x, w1.y, w1.z, w1.w,
                            w2.x, w2.y, w2.z, w2.w};
#pragma unroll
            for (int i = 0; i < 8; ++i)
#pragma unroll
                for (int j = 0; j < 12; ++j)
                    acc[i][j] += xr[i] * wr[j];
        }
        __syncthreads();
    }

#pragma unroll
    for (int i = 0; i < 8; ++i) {
        int gr = row0 + tm + i;
        if (gr >= rows) continue;
#pragma unroll
        for (int c = 0; c < 3; ++c)
#pragma unroll
            for (int j = 0; j < 4; ++j) {
                int cn = tn + c * 64 + j;
                if (cn < 150) P[(long)gr * 300 + cn] = acc[i][c * 4 + j];
            }
    }
}

// ---------------------------------------------------------------------------
// Half-column bond update (128x64 tiles, K=147), true double-buffered LDS:
// one barrier per K-iteration (same transform as gemm_big).
// ---------------------------------------------------------------------------
__global__ __launch_bounds__(256)
void bond_half(const float* __restrict__ FB, const float* __restrict__ WiB,
               const float* __restrict__ Th, const float* __restrict__ Vsrc, int vstride,
               const int* __restrict__ b2a, const int* __restrict__ b2revb,
               float* __restrict__ P, int c0, int rows)
{
    __shared__ float Xs[2][16][132];
    __shared__ float Ws[2][16][68];
    __shared__ int ra[128], rb[128];
    const int row0 = blockIdx.x * 128;
    const int col0 = blockIdx.y * 64;
    const int tid  = threadIdx.x;

    if (tid < 128) {
        int gr = row0 + tid;
        ra[tid] = (gr < rows) ? b2a[gr] : 0;
    } else {
        int m = tid - 128;
        int gr = row0 + m;
        rb[m] = (gr < rows) ? b2revb[gr] : 0;
    }

    const int tm = (tid >> 4) * 8;
    const int tn = (tid & 15) * 4;

    float px[2][4], pw[4];

    auto loadTile = [&](int k0) {
        const int rem = BFD - k0;
#pragma unroll
        for (int l = 0; l < 2; ++l) {
            int s = tid + l * 256;
            int r = s >> 2, kq = (s & 3) * 4;
            int gr = row0 + r;
            float v0 = 0, v1 = 0, v2 = 0, v3 = 0;
            if (gr < rows) {
                const float* xp = FB + (long)gr * BFD + k0 + kq;
                if (kq + 0 < rem) v0 = xp[0];
                if (kq + 1 < rem) v1 = xp[1];
                if (kq + 2 < rem) v2 = xp[2];
                if (kq + 3 < rem) v3 = xp[3];
            }
            px[l][0] = v0; px[l][1] = v1; px[l][2] = v2; px[l][3] = v3;
        }
        {
            int r = tid >> 2, kq = (tid & 3) * 4;
            int gc = col0 + r;
            float v0 = 0, v1 = 0, v2 = 0, v3 = 0;
            if (gc < 150) {
                const float* wp = WiB + (long)(c0 + gc) * BFD + k0 + kq;
                if (kq + 0 < rem) v0 = wp[0];
                if (kq + 1 < rem) v1 = wp[1];
                if (kq + 2 < rem) v2 = wp[2];
                if (kq + 3 < rem) v3 = wp[3];
            }
            pw[0] = v0; pw[1] = v1; pw[2] = v2; pw[3] = v3;
        }
    };
    auto commitTile = [&](int buf) {
#pragma unroll
        for (int l = 0; l < 2; ++l) {
            int s = tid + l * 256;
            int r = s >> 2, kq = (s & 3) * 4;
            Xs[buf][kq + 0][r] = px[l][0]; Xs[buf][kq + 1][r] = px[l][1];
            Xs[buf][kq + 2][r] = px[l][2]; Xs[buf][kq + 3][r] = px[l][3];
        }
        {
            int r = tid >> 2, kq = (tid & 3) * 4;
            Ws[buf][kq + 0][r] = pw[0]; Ws[buf][kq + 1][r] = pw[1];
            Ws[buf][kq + 2][r] = pw[2]; Ws[buf][kq + 3][r] = pw[3];
        }
    };

    float acc[8][4];
#pragma unroll
    for (int i = 0; i < 8; ++i)
#pragma unroll
        for (int j = 0; j < 4; ++j) acc[i][j] = 0.0f;

    loadTile(0);
    commitTile(0);
    __syncthreads();

    int cur = 0;
    for (int k0 = 0; k0 < BFD; k0 += 16) {
        const bool more = (k0 + 16 < BFD);
        if (more) loadTile(k0 + 16);
#pragma unroll
        for (int kk = 0; kk < 16; ++kk) {
            float4 xa = *(const float4*)&Xs[cur][kk][tm];
            float4 xb = *(const float4*)&Xs[cur][kk][tm + 4];
            float4 wq = *(const float4*)&Ws[cur][kk][tn];
            float xr[8] = {xa.x, xa.y, xa.z, xa.w, xb.x, xb.y, xb.z, xb.w};
            float wr[4] = {wq.x, wq.y, wq.z, wq.w};
#pragma unroll
            for (int i = 0; i < 8; ++i)
#pragma unroll
                for (int j = 0; j < 4; ++j)
                    acc[i][j] += xr[i] * wr[j];
        }
        if (more) commitTile(cur ^ 1);
        __syncthreads();
        cur ^= 1;
    }

#pragma unroll
    for (int i = 0; i < 8; ++i) {
        int gr = row0 + tm + i;
        if (gr >= rows) continue;
        int a  = ra[tm + i];
        int rv = rb[tm + i];
#pragma unroll
        for (int j = 0; j < 4; ++j) {
            int cn = col0 + tn + j;
            if (cn >= 150) continue;
            float ib = fmaxf(acc[i][j], 0.0f);
            float v  = ib + Th[(long)a * 150 + cn] - Vsrc[(long)rv * vstride + cn];
            P[(long)gr * 300 + c0 + cn] = fmaxf(v, 0.0f);
        }
    }
}

template<bool ADD>
__global__ void aggregate(const float* __restrict__ mb, const int* __restrict__ a2b,
                          float* __restrict__ dst)
{
    long idx = (long)blockIdx.x * blockDim.x + threadIdx.x;
    if (idx >= (long)AA * HH) return;
    int a = (int)(idx / HH);
    int h = (int)(idx - (long)a * HH);
    const int* nb = a2b + (long)a * NBB;
    float s = 0.0f, mx = -INFINITY;
#pragma unroll
    for (int i = 0; i < NBB; ++i) {
        float v = mb[(long)nb[i] * HH + h];
        s += v;
        mx = fmaxf(mx, v);
    }
    float r = s * mx;
    if (ADD) r += dst[idx];
    dst[idx] = r;
}

__global__ void msgx_kernel(const float* __restrict__ node, const float* __restrict__ gbias,
                            float* __restrict__ msgx)
{
    long idx = (long)blockIdx.x * blockDim.x + threadIdx.x;
    if (idx >= (long)MLR * HH) return;
    int h = (int)(idx % HH);
    msgx[idx] = fmaxf(node[idx + HH] + gbias[h], 0.0f);
}

__global__ void h0_kernel(const float* __restrict__ node, float* __restrict__ hf)
{
    int idx = blockIdx.x * blockDim.x + threadIdx.x;
    if (idx >= MMOL * HH) return;
    int m = idx / HH;
    int h = idx - m * HH;
    long base = (long)(1 + m * LATM) * HH + h;
    float mx = -INFINITY;
    for (int t = 0; t < LATM; ++t) mx = fmaxf(mx, node[base + (long)t * HH]);
    hf[idx] = mx;
}

// ---------------------------------------------------------------------------
// GRU scan v3q (proven): 256 blocks, 2 mols, XCD-pinned dirs, WQ interleaved
// weights (one coalesced float4 per 4-k chunk). gout in-place into gi.
// ---------------------------------------------------------------------------
__global__ __launch_bounds__(1024)
void gru_scan3(const float* __restrict__ WQ_f, const float* __restrict__ bhh_f,
               const float* __restrict__ WQ_b, const float* __restrict__ bhh_b,
               const float* __restrict__ h0, float* __restrict__ gi_f,
               float* __restrict__ gi_b)
{
    const int bid  = blockIdx.x;
    const int xcd  = bid & 7;
    const int dir  = (xcd >= 4) ? 1 : 0;
    const int rank = (bid >> 3) * 4 + (xcd & 3);   // 0..127, bijective per dir
    const int m0   = rank * 2;
    const float* WQ  = dir ? WQ_b  : WQ_f;
    const float* bhh = dir ? bhh_b : bhh_f;
    float*       gi  = dir ? gi_b  : gi_f;
    const int tid = threadIdx.x;

    __shared__ float hs[2][304];
    __shared__ float ghs[2][H3];

    float bb = (tid < H3) ? bhh[tid] : 0.0f;

    for (int i = tid; i < 150; i += 1024) {
        int mm = i / 75, q = (i - mm * 75) * 4;
        *(float4*)&hs[mm][q] = *(const float4*)&h0[(long)(m0 + mm) * HH + q];
    }
    __syncthreads();

    for (int s = 0; s < LATM; ++s) {
        const int t = dir ? (LATM - 1 - s) : s;

        if (tid < H3) {
            float a0 = 0.0f, a1 = 0.0f;
            const float* wq = WQ + (long)tid * 4;
#pragma unroll 4
            for (int k0 = 0; k0 < HH; k0 += 4) {
                float4 w = *(const float4*)wq;
                wq += 3600;
                float4 h0v = *(const float4*)&hs[0][k0];
                float4 h1v = *(const float4*)&hs[1][k0];
                a0 += h0v.x * w.x + h0v.y * w.y + h0v.z * w.z + h0v.w * w.w;
                a1 += h1v.x * w.x + h1v.y * w.y + h1v.z * w.z + h1v.w * w.w;
            }
            ghs[0][tid] = a0 + bb;
            ghs[1][tid] = a1 + bb;
        }
        __syncthreads();

        if (tid < 2 * HH) {
            int mm = tid / HH, hh = tid - mm * HH;
            long row = (long)(m0 + mm) * LATM + t;
            float* g = gi + row * H3;
            float ir = g[hh], iz = g[HH + hh], inn = g[2 * HH + hh];
            float r  = sigm(ir + ghs[mm][hh]);
            float z  = sigm(iz + ghs[mm][HH + hh]);
            float nn = tanhf(inn + r * ghs[mm][2 * HH + hh]);
            float hn = (1.0f - z) * nn + z * hs[mm][hh];
            hs[mm][hh] = hn;
            g[hh] = hn;
        }
        __syncthreads();
    }
}

__global__ void mean_kernel(const float* __restrict__ ah, float* __restrict__ out)
{
    int idx = blockIdx.x * blockDim.x + threadIdx.x;
    if (idx >= MMOL * HH) return;
    int m = idx / HH;
    int j = idx - m * HH;
    long base = (long)m * LATM * HH + j;
    float s = 0.0f;
    for (int t = 0; t < LATM; ++t) s += ah[base + (long)t * HH];
    out[idx] = s * (1.0f / LATM);
}

// ---------------------------------------------------------------------------
static inline int cdiv(long a, long b) { return (int)((a + b - 1) / b); }

extern "C" void kernel_launch(void* const* d_in, const int* in_sizes, int n_in,
                              void* d_out, int out_size, void* d_ws, size_t ws_size,
                              hipStream_t stream)
{
    const float* f_atoms  = (const float*)d_in[0];
    const float* f_bonds  = (const float*)d_in[1];
    const int*   a2b      = (const int*)d_in[2];
    const int*   b2a      = (const int*)d_in[3];
    const int*   b2revb   = (const int*)d_in[4];
    const float* W_i_atom = (const float*)d_in[5];
    const float* W_i_bond = (const float*)d_in[6];
    const float* W_h0     = (const float*)d_in[7];
    const float* W_h1     = (const float*)d_in[8];
    const float* W_lr     = (const float*)d_in[9];
    const float* gru_bias = (const float*)d_in[10];
    const float* Wih_f    = (const float*)d_in[11];
    const float* Whh_f    = (const float*)d_in[12];
    const float* bih_f    = (const float*)d_in[13];
    const float* bhh_f    = (const float*)d_in[14];
    const float* Wih_b    = (const float*)d_in[15];
    const float* Whh_b    = (const float*)d_in[16];
    const float* bih_b    = (const float*)d_in[17];
    const float* bhh_b    = (const float*)d_in[18];
    const float* W_o      = (const float*)d_in[19];
    const float* b_o      = (const float*)d_in[20];
    float* out = (float*)d_out;

    // fp32 arena (total 295,530,016 <= proven ws floor).
    // Depth-loop regions: P@0, S@157287600, MA@235931408, TH@275254208.
    // Scan overlays: gi_f@0, gi_b@117964800, msgx/AH in MA, h0 + WQ_f/b in TH.
    const size_t NEED = 295530016;
    if (ws_size < NEED) return;

    char* b = (char*)d_ws;
    float* P   = (float*)b;
    float* S   = (float*)(b + 157287600);
    float* MA  = (float*)(b + 235931408);
    float* TH  = (float*)(b + 275254208);

    float* Pia  = P + (size_t)AA * HH;        // ia_rc [A,300]
    float* giF  = (float*)b;                  // [ML,900]
    float* giB  = (float*)(b + 117964800);    // [ML,900]
    float* MSGX = MA;                         // [ML,300] (MA dead post-node)
    float* AH   = MA;                         // atomhid [ML,300]
    float* H0   = TH;                         // [M,300]
    float* WQ_f = TH + 76800;                 // 270,000 floats
    float* WQ_b = TH + 346800;                // 270,000 floats

    dim3 blk(256);
    const int gA = cdiv((long)AA * HH, 256);
    dim3 gmA (cdiv(AA, 128),   cdiv(HH, 64));
    dim3 gmB3(cdiv(BBND, 128), cdiv(HH, 64));
    dim3 gmB1(cdiv(BBND, 128), cdiv(150, 64));
    dim3 gmT (cdiv(AA, 128),   cdiv(150, 64));
    dim3 gmG (cdiv(MLR, 128),  cdiv(H3, 64));
    dim3 gmO (cdiv(MLR, 128),  cdiv(HH, 64));

    // 1. ma = input_atom ; 2. mb0 = input_bond -> P
    gemm_big<true, false, false><<<gmA, blk, 0, stream>>>(
        f_atoms, AFD, W_i_atom, AFD, nullptr, MA, AA, HH, AFD);
    gemm_big<true, false, false><<<gmB3, blk, 0, stream>>>(
        f_bonds, BFD, W_i_bond, BFD, nullptr, P, BBND, HH, BFD);

    // Depth loop
    const float* Wh[2] = { W_h0, W_h1 };
    for (int d = 0; d < 2; ++d) {
        const float* W = Wh[d];
        aggregate<true><<<gA, blk, 0, stream>>>(P, a2b, MA);
        gemm_big<false, false, false><<<gmB1, blk, 0, stream>>>(
            P, HH, W, HH, nullptr, S, BBND, 150, HH);
        vw_hi_gemm<<<cdiv(BBND, 128), blk, 0, stream>>>(P, W, BBND);
        gemm_big<false, false, false><<<gmT, blk, 0, stream>>>(
            MA, HH, W + 150 * HH, HH, nullptr, TH, AA, 150, HH);
        bond_half<<<gmB1, blk, 0, stream>>>(
            f_bonds, W_i_bond, TH, P, 300, b2a, b2revb, P, 150, BBND);
        gemm_big<false, false, false><<<gmT, blk, 0, stream>>>(
            MA, HH, W, HH, nullptr, TH, AA, 150, HH);
        bond_half<<<gmB1, blk, 0, stream>>>(
            f_bonds, W_i_bond, TH, S, 150, b2a, b2revb, P, 0, BBND);
    }

    // Final aggregation -> S
    aggregate<false><<<gA, blk, 0, stream>>>(P, a2b, S);

    // ia recomputed -> Pia ; node -> P[0:A*300)
    gemm_big<true, false, false><<<gmA, blk, 0, stream>>>(
        f_atoms, AFD, W_i_atom, AFD, nullptr, Pia, AA, HH, AFD);
    gemm_big<false, false, false><<<gmA, blk, 0, stream>>>(
        S,   HH, W_lr,          H3, nullptr, P, AA, HH, HH);
    gemm_big<false, false, true><<<gmA, blk, 0, stream>>>(
        MA,  HH, W_lr + HH,     H3, nullptr, P, AA, HH, HH);
    gemm_big<false, false, true><<<gmA, blk, 0, stream>>>(
        Pia, HH, W_lr + 2 * HH, H3, nullptr, P, AA, HH, HH);

    // GRU prep: msgx -> MA region, h0 -> TH, WQ interleaved transposes -> TH
    msgx_kernel<<<cdiv((long)MLR * HH, 256), blk, 0, stream>>>(P, gru_bias, MSGX);
    h0_kernel<<<cdiv(MMOL * HH, 256), blk, 0, stream>>>(P, H0);
    transposeQ<<<cdiv(270000, 256), blk, 0, stream>>>(Whh_f, WQ_f);
    transposeQ<<<cdiv(270000, 256), blk, 0, stream>>>(Whh_b, WQ_b);

    // gi = msgx @ Wih^T + bih (both dirs; overwrites node/mb/agg — all dead)
    gemm_big<false, true, false><<<gmG, blk, 0, stream>>>(
        MSGX, HH, Wih_f, HH, bih_f, giF, MLR, H3, HH);
    gemm_big<false, true, false><<<gmG, blk, 0, stream>>>(
        MSGX, HH, Wih_b, HH, bih_b, giB, MLR, H3, HH);

    // Fused bidirectional scan (gout in-place into gi[t][0:300])
    gru_scan3<<<dim3(256), dim3(1024), 0, stream>>>(
        WQ_f, bhh_f, WQ_b, bhh_b, H0, giF, giB);

    // atom_hiddens = relu(gout_f@Wo_lo^T + gout_b@Wo_hi^T + b_o) -> AH
    gemm_big<false, false, false><<<gmO, blk, 0, stream>>>(
        giF, H3, W_o,      2 * HH, nullptr, AH, MLR, HH, HH);
    gemm_big<true, true, true><<<gmO, blk, 0, stream>>>(
        giB, H3, W_o + HH, 2 * HH, b_o,     AH, MLR, HH, HH);

    // mol_vecs -> out
    mean_kernel<<<cdiv(MMOL * HH, 256), blk, 0, stream>>>(AH, out);
}

// Round 13
// 5700.107 us; speedup vs baseline: 1.2337x; 1.2337x over previous
//
#include <hip/hip_runtime.h>
#include <math.h>

// Problem constants
#define HH   300
#define H3   900
#define MMOL 256
#define LATM 128
#define AA   32769        // 1 + 256*128
#define NBB  6
#define BBND 131073       // 1 + 4*256*128
#define AFD  133
#define BFD  147
#define MLR  (MMOL * LATM)   // 32768

static __device__ __forceinline__ float sigm(float x) { return 1.0f / (1.0f + expf(-x)); }

// ---------------------------------------------------------------------------
// Tiled fp32 GEMM, 128x64 tile, BK=16, 8x4 microtile, 256 threads.
// Register-prefetch, single LDS buffer (round-11 proven config; dbuf LDS
// halves occupancy and regresses — round-12 measured).
// ---------------------------------------------------------------------------
template<bool RELU, bool BIAS, bool ACCUM>
__global__ __launch_bounds__(256)
void gemm_big(const float* __restrict__ X, int ldx, const float* __restrict__ W, int ldw,
              const float* __restrict__ Bias, float* __restrict__ C,
              int rows, int N, int K)
{
    __shared__ float Xs[16][132];
    __shared__ float Ws[16][68];
    const int row0 = blockIdx.x * 128;
    const int col0 = blockIdx.y * 64;
    const int tid  = threadIdx.x;
    const int tm   = (tid >> 4) * 8;
    const int tn   = (tid & 15) * 4;
    const bool xv  = ((ldx & 3) == 0);
    const bool wv  = ((ldw & 3) == 0);

    float px[2][4], pw[4];

    auto loadTile = [&](int k0) {
        const int rem = K - k0;
#pragma unroll
        for (int l = 0; l < 2; ++l) {
            int s = tid + l * 256;
            int r = s >> 2, kq = (s & 3) * 4;
            int gr = row0 + r;
            float v0 = 0, v1 = 0, v2 = 0, v3 = 0;
            if (gr < rows) {
                const float* xp = X + (long)gr * ldx + k0 + kq;
                if (xv && rem >= 16) {
                    float4 t4 = *(const float4*)xp;
                    v0 = t4.x; v1 = t4.y; v2 = t4.z; v3 = t4.w;
                } else {
                    if (kq + 0 < rem) v0 = xp[0];
                    if (kq + 1 < rem) v1 = xp[1];
                    if (kq + 2 < rem) v2 = xp[2];
                    if (kq + 3 < rem) v3 = xp[3];
                }
            }
            px[l][0] = v0; px[l][1] = v1; px[l][2] = v2; px[l][3] = v3;
        }
        {
            int r = tid >> 2, kq = (tid & 3) * 4;
            int gc = col0 + r;
            float v0 = 0, v1 = 0, v2 = 0, v3 = 0;
            if (gc < N) {
                const float* wp = W + (long)gc * ldw + k0 + kq;
                if (wv && rem >= 16) {
                    float4 t4 = *(const float4*)wp;
                    v0 = t4.x; v1 = t4.y; v2 = t4.z; v3 = t4.w;
                } else {
                    if (kq + 0 < rem) v0 = wp[0];
                    if (kq + 1 < rem) v1 = wp[1];
                    if (kq + 2 < rem) v2 = wp[2];
                    if (kq + 3 < rem) v3 = wp[3];
                }
            }
            pw[0] = v0; pw[1] = v1; pw[2] = v2; pw[3] = v3;
        }
    };
    auto commitTile = [&]() {
#pragma unroll
        for (int l = 0; l < 2; ++l) {
            int s = tid + l * 256;
            int r = s >> 2, kq = (s & 3) * 4;
            Xs[kq + 0][r] = px[l][0]; Xs[kq + 1][r] = px[l][1];
            Xs[kq + 2][r] = px[l][2]; Xs[kq + 3][r] = px[l][3];
        }
        {
            int r = tid >> 2, kq = (tid & 3) * 4;
            Ws[kq + 0][r] = pw[0]; Ws[kq + 1][r] = pw[1];
            Ws[kq + 2][r] = pw[2]; Ws[kq + 3][r] = pw[3];
        }
    };

    float acc[8][4];
#pragma unroll
    for (int i = 0; i < 8; ++i)
#pragma unroll
        for (int j = 0; j < 4; ++j) acc[i][j] = 0.0f;

    loadTile(0);
    for (int k0 = 0; k0 < K; k0 += 16) {
        commitTile();
        __syncthreads();
        if (k0 + 16 < K) loadTile(k0 + 16);
#pragma unroll
        for (int kk = 0; kk < 16; ++kk) {
            float4 xa = *(const float4*)&Xs[kk][tm];
            float4 xb = *(const float4*)&Xs[kk][tm + 4];
            float4 wq = *(const float4*)&Ws[kk][tn];
            float xr[8] = {xa.x, xa.y, xa.z, xa.w, xb.x, xb.y, xb.z, xb.w};
            float wr[4] = {wq.x, wq.y, wq.z, wq.w};
#pragma unroll
            for (int i = 0; i < 8; ++i)
#pragma unroll
                for (int j = 0; j < 4; ++j)
                    acc[i][j] += xr[i] * wr[j];
        }
        __syncthreads();
    }

#pragma unroll
    for (int i = 0; i < 8; ++i) {
        int gr = row0 + tm + i;
        if (gr >= rows) continue;
#pragma unroll
        for (int j = 0; j < 4; ++j) {
            int gc = col0 + tn + j;
            if (gc >= N) continue;
            float v = acc[i][j];
            if (BIAS)  v += Bias[gc];
            if (ACCUM) v += C[(long)gr * N + gc];
            if (RELU)  v = fmaxf(v, 0.0f);
            C[(long)gr * N + gc] = v;
        }
    }
}

// transposeQ: Whh[900][300] -> WQ[(k/4)][n][4]  (float4-loadable per gate n)
__global__ void transposeQ(const float* __restrict__ in, float* __restrict__ out)
{
    long idx = (long)blockIdx.x * blockDim.x + threadIdx.x;
    if (idx >= 270000) return;
    int n = (int)(idx / 300), k = (int)(idx - (long)n * 300);
    out[(long)(k >> 2) * 3600 + n * 4 + (k & 3)] = in[idx];
}

// ---------------------------------------------------------------------------
// vw_gemm: full-150-col-stripe GEMM over X=P (proven vw_hi_gemm shape).
//   Cout[r*ldc + cn] = (P[r, 0:300) @ W[wrow0 + cn, :]^T),  cn in [0,150)
// One block owns a 128-row stripe and ALL 150 cols: X staged once (vs 3x in
// gemm_big's 64-col blocks), 96 FMAs per 5 ds_read_b128.
// In-place safe when Cout==P (reads own rows only, epilogue-only writes).
// Ascending-k accumulation — bit-identical to the gemm_big path it replaces.
// ---------------------------------------------------------------------------
__global__ __launch_bounds__(256)
void vw_gemm(const float* __restrict__ X, const float* __restrict__ W, int wrow0,
             float* __restrict__ Cout, int ldc, int rows)
{
    __shared__ float Xs[16][132];
    __shared__ float Ws[16][192];
    const int row0 = blockIdx.x * 128;
    const int tid  = threadIdx.x;
    const int tm   = (tid >> 4) * 8;
    const int tn   = (tid & 15) * 4;

    float acc[8][12];
#pragma unroll
    for (int i = 0; i < 8; ++i)
#pragma unroll
        for (int j = 0; j < 12; ++j) acc[i][j] = 0.0f;

    for (int k0 = 0; k0 < 300; k0 += 16) {
        const int rem = 300 - k0;
#pragma unroll
        for (int l = 0; l < 2; ++l) {
            int s = tid + l * 256;
            int r = s >> 2, kq = (s & 3) * 4;
            int gr = row0 + r;
            float v0 = 0, v1 = 0, v2 = 0, v3 = 0;
            if (gr < rows) {
                const float* xp = X + (long)gr * 300 + k0 + kq;
                if (rem >= 16) {
                    float4 t4 = *(const float4*)xp;
                    v0 = t4.x; v1 = t4.y; v2 = t4.z; v3 = t4.w;
                } else {
                    if (kq + 0 < rem) v0 = xp[0];
                    if (kq + 1 < rem) v1 = xp[1];
                    if (kq + 2 < rem) v2 = xp[2];
                    if (kq + 3 < rem) v3 = xp[3];
                }
            }
            Xs[kq + 0][r] = v0; Xs[kq + 1][r] = v1;
            Xs[kq + 2][r] = v2; Xs[kq + 3][r] = v3;
        }
        for (int s = tid; s < 600; s += 256) {
            int r = s >> 2, kq = (s & 3) * 4;
            const float* wp = W + (long)(wrow0 + r) * 300 + k0 + kq;
            float v0 = 0, v1 = 0, v2 = 0, v3 = 0;
            if (rem >= 16) {
                float4 t4 = *(const float4*)wp;
                v0 = t4.x; v1 = t4.y; v2 = t4.z; v3 = t4.w;
            } else {
                if (kq + 0 < rem) v0 = wp[0];
                if (kq + 1 < rem) v1 = wp[1];
                if (kq + 2 < rem) v2 = wp[2];
                if (kq + 3 < rem) v3 = wp[3];
            }
            Ws[kq + 0][r] = v0; Ws[kq + 1][r] = v1;
            Ws[kq + 2][r] = v2; Ws[kq + 3][r] = v3;
        }
        __syncthreads();
#pragma unroll
        for (int kk = 0; kk < 16; ++kk) {
            float4 xa = *(const float4*)&Xs[kk][tm];
            float4 xb = *(const float4*)&Xs[kk][tm + 4];
            float4 w0 = *(const float4*)&Ws[kk][tn];
            float4 w1 = *(const float4*)&Ws[kk][tn + 64];
            float4 w2 = *(const float4*)&Ws[kk][tn + 128];
            float xr[8] = {xa.x, xa.y, xa.z, xa.w, xb.x, xb.y, xb.z, xb.w};
            float wr[12] = {w0.x, w0.y, w0.z, w0.w, w1.x, w1.y, w1.z, w1.w,
                            w2.x, w2.y, w2.z, w2.w};
#pragma unroll
            for (int i = 0; i < 8; ++i)
#pragma unroll
                for (int j = 0; j < 12; ++j)
                    acc[i][j] += xr[i] * wr[j];
        }
        __syncthreads();
    }

#pragma unroll
    for (int i = 0; i < 8; ++i) {
        int gr = row0 + tm + i;
        if (gr >= rows) continue;
#pragma unroll
        for (int c = 0; c < 3; ++c)
#pragma unroll
            for (int j = 0; j < 4; ++j) {
                int cn = tn + c * 64 + j;
                if (cn < 150) Cout[(long)gr * ldc + cn] = acc[i][c * 4 + j];
            }
    }
}

// ---------------------------------------------------------------------------
// Half-column bond update (128x64 tiles, K=147 recomputed input_bond)
// ---------------------------------------------------------------------------
__global__ __launch_bounds__(256)
void bond_half(const float* __restrict__ FB, const float* __restrict__ WiB,
               const float* __restrict__ Th, const float* __restrict__ Vsrc, int vstride,
               const int* __restrict__ b2a, const int* __restrict__ b2revb,
               float* __restrict__ P, int c0, int rows)
{
    __shared__ float Xs[16][132];
    __shared__ float Ws[16][68];
    __shared__ int ra[128], rb[128];
    const int row0 = blockIdx.x * 128;
    const int col0 = blockIdx.y * 64;
    const int tid  = threadIdx.x;

    if (tid < 128) {
        int gr = row0 + tid;
        ra[tid] = (gr < rows) ? b2a[gr] : 0;
    } else {
        int m = tid - 128;
        int gr = row0 + m;
        rb[m] = (gr < rows) ? b2revb[gr] : 0;
    }

    const int tm = (tid >> 4) * 8;
    const int tn = (tid & 15) * 4;
    float acc[8][4];
#pragma unroll
    for (int i = 0; i < 8; ++i)
#pragma unroll
        for (int j = 0; j < 4; ++j) acc[i][j] = 0.0f;

    for (int k0 = 0; k0 < BFD; k0 += 16) {
        const int rem = BFD - k0;
#pragma unroll
        for (int l = 0; l < 2; ++l) {
            int s = tid + l * 256;
            int r = s >> 2, kq = (s & 3) * 4;
            int gr = row0 + r;
            float v0 = 0, v1 = 0, v2 = 0, v3 = 0;
            if (gr < rows) {
                const float* xp = FB + (long)gr * BFD + k0 + kq;
                if (kq + 0 < rem) v0 = xp[0];
                if (kq + 1 < rem) v1 = xp[1];
                if (kq + 2 < rem) v2 = xp[2];
                if (kq + 3 < rem) v3 = xp[3];
            }
            Xs[kq + 0][r] = v0; Xs[kq + 1][r] = v1;
            Xs[kq + 2][r] = v2; Xs[kq + 3][r] = v3;
        }
        {
            int r = tid >> 2, kq = (tid & 3) * 4;
            int gc = col0 + r;
            float v0 = 0, v1 = 0, v2 = 0, v3 = 0;
            if (gc < 150) {
                const float* wp = WiB + (long)(c0 + gc) * BFD + k0 + kq;
                if (kq + 0 < rem) v0 = wp[0];
                if (kq + 1 < rem) v1 = wp[1];
                if (kq + 2 < rem) v2 = wp[2];
                if (kq + 3 < rem) v3 = wp[3];
            }
            Ws[kq + 0][r] = v0; Ws[kq + 1][r] = v1;
            Ws[kq + 2][r] = v2; Ws[kq + 3][r] = v3;
        }
        __syncthreads();
#pragma unroll
        for (int kk = 0; kk < 16; ++kk) {
            float4 xa = *(const float4*)&Xs[kk][tm];
            float4 xb = *(const float4*)&Xs[kk][tm + 4];
            float4 wq = *(const float4*)&Ws[kk][tn];
            float xr[8] = {xa.x, xa.y, xa.z, xa.w, xb.x, xb.y, xb.z, xb.w};
            float wr[4] = {wq.x, wq.y, wq.z, wq.w};
#pragma unroll
            for (int i = 0; i < 8; ++i)
#pragma unroll
                for (int j = 0; j < 4; ++j)
                    acc[i][j] += xr[i] * wr[j];
        }
        __syncthreads();
    }

#pragma unroll
    for (int i = 0; i < 8; ++i) {
        int gr = row0 + tm + i;
        if (gr >= rows) continue;
        int a  = ra[tm + i];
        int rv = rb[tm + i];
#pragma unroll
        for (int j = 0; j < 4; ++j) {
            int cn = col0 + tn + j;
            if (cn >= 150) continue;
            float ib = fmaxf(acc[i][j], 0.0f);
            float v  = ib + Th[(long)a * 150 + cn] - Vsrc[(long)rv * vstride + cn];
            P[(long)gr * 300 + c0 + cn] = fmaxf(v, 0.0f);
        }
    }
}

template<bool ADD>
__global__ void aggregate(const float* __restrict__ mb, const int* __restrict__ a2b,
                          float* __restrict__ dst)
{
    long idx = (long)blockIdx.x * blockDim.x + threadIdx.x;
    if (idx >= (long)AA * HH) return;
    int a = (int)(idx / HH);
    int h = (int)(idx - (long)a * HH);
    const int* nb = a2b + (long)a * NBB;
    float s = 0.0f, mx = -INFINITY;
#pragma unroll
    for (int i = 0; i < NBB; ++i) {
        float v = mb[(long)nb[i] * HH + h];
        s += v;
        mx = fmaxf(mx, v);
    }
    float r = s * mx;
    if (ADD) r += dst[idx];
    dst[idx] = r;
}

__global__ void msgx_kernel(const float* __restrict__ node, const float* __restrict__ gbias,
                            float* __restrict__ msgx)
{
    long idx = (long)blockIdx.x * blockDim.x + threadIdx.x;
    if (idx >= (long)MLR * HH) return;
    int h = (int)(idx % HH);
    msgx[idx] = fmaxf(node[idx + HH] + gbias[h], 0.0f);
}

__global__ void h0_kernel(const float* __restrict__ node, float* __restrict__ hf)
{
    int idx = blockIdx.x * blockDim.x + threadIdx.x;
    if (idx >= MMOL * HH) return;
    int m = idx / HH;
    int h = idx - m * HH;
    long base = (long)(1 + m * LATM) * HH + h;
    float mx = -INFINITY;
    for (int t = 0; t < LATM; ++t) mx = fmaxf(mx, node[base + (long)t * HH]);
    hf[idx] = mx;
}

// ---------------------------------------------------------------------------
// GRU scan v3q (proven): 256 blocks, 2 mols, XCD-pinned dirs, WQ interleaved
// weights (one coalesced float4 per 4-k chunk). gout in-place into gi.
// ---------------------------------------------------------------------------
__global__ __launch_bounds__(1024)
void gru_scan3(const float* __restrict__ WQ_f, const float* __restrict__ bhh_f,
               const float* __restrict__ WQ_b, const float* __restrict__ bhh_b,
               const float* __restrict__ h0, float* __restrict__ gi_f,
               float* __restrict__ gi_b)
{
    const int bid  = blockIdx.x;
    const int xcd  = bid & 7;
    const int dir  = (xcd >= 4) ? 1 : 0;
    const int rank = (bid >> 3) * 4 + (xcd & 3);   // 0..127, bijective per dir
    const int m0   = rank * 2;
    const float* WQ  = dir ? WQ_b  : WQ_f;
    const float* bhh = dir ? bhh_b : bhh_f;
    float*       gi  = dir ? gi_b  : gi_f;
    const int tid = threadIdx.x;

    __shared__ float hs[2][304];
    __shared__ float ghs[2][H3];

    float bb = (tid < H3) ? bhh[tid] : 0.0f;

    for (int i = tid; i < 150; i += 1024) {
        int mm = i / 75, q = (i - mm * 75) * 4;
        *(float4*)&hs[mm][q] = *(const float4*)&h0[(long)(m0 + mm) * HH + q];
    }
    __syncthreads();

    for (int s = 0; s < LATM; ++s) {
        const int t = dir ? (LATM - 1 - s) : s;

        if (tid < H3) {
            float a0 = 0.0f, a1 = 0.0f;
            const float* wq = WQ + (long)tid * 4;
#pragma unroll 4
            for (int k0 = 0; k0 < HH; k0 += 4) {
                float4 w = *(const float4*)wq;
                wq += 3600;
                float4 h0v = *(const float4*)&hs[0][k0];
                float4 h1v = *(const float4*)&hs[1][k0];
                a0 += h0v.x * w.x + h0v.y * w.y + h0v.z * w.z + h0v.w * w.w;
                a1 += h1v.x * w.x + h1v.y * w.y + h1v.z * w.z + h1v.w * w.w;
            }
            ghs[0][tid] = a0 + bb;
            ghs[1][tid] = a1 + bb;
        }
        __syncthreads();

        if (tid < 2 * HH) {
            int mm = tid / HH, hh = tid - mm * HH;
            long row = (long)(m0 + mm) * LATM + t;
            float* g = gi + row * H3;
            float ir = g[hh], iz = g[HH + hh], inn = g[2 * HH + hh];
            float r  = sigm(ir + ghs[mm][hh]);
            float z  = sigm(iz + ghs[mm][HH + hh]);
            float nn = tanhf(inn + r * ghs[mm][2 * HH + hh]);
            float hn = (1.0f - z) * nn + z * hs[mm][hh];
            hs[mm][hh] = hn;
            g[hh] = hn;
        }
        __syncthreads();
    }
}

__global__ void mean_kernel(const float* __restrict__ ah, float* __restrict__ out)
{
    int idx = blockIdx.x * blockDim.x + threadIdx.x;
    if (idx >= MMOL * HH) return;
    int m = idx / HH;
    int j = idx - m * HH;
    long base = (long)m * LATM * HH + j;
    float s = 0.0f;
    for (int t = 0; t < LATM; ++t) s += ah[base + (long)t * HH];
    out[idx] = s * (1.0f / LATM);
}

// ---------------------------------------------------------------------------
static inline int cdiv(long a, long b) { return (int)((a + b - 1) / b); }

extern "C" void kernel_launch(void* const* d_in, const int* in_sizes, int n_in,
                              void* d_out, int out_size, void* d_ws, size_t ws_size,
                              hipStream_t stream)
{
    const float* f_atoms  = (const float*)d_in[0];
    const float* f_bonds  = (const float*)d_in[1];
    const int*   a2b      = (const int*)d_in[2];
    const int*   b2a      = (const int*)d_in[3];
    const int*   b2revb   = (const int*)d_in[4];
    const float* W_i_atom = (const float*)d_in[5];
    const float* W_i_bond = (const float*)d_in[6];
    const float* W_h0     = (const float*)d_in[7];
    const float* W_h1     = (const float*)d_in[8];
    const float* W_lr     = (const float*)d_in[9];
    const float* gru_bias = (const float*)d_in[10];
    const float* Wih_f    = (const float*)d_in[11];
    const float* Whh_f    = (const float*)d_in[12];
    const float* bih_f    = (const float*)d_in[13];
    const float* bhh_f    = (const float*)d_in[14];
    const float* Wih_b    = (const float*)d_in[15];
    const float* Whh_b    = (const float*)d_in[16];
    const float* bih_b    = (const float*)d_in[17];
    const float* bhh_b    = (const float*)d_in[18];
    const float* W_o      = (const float*)d_in[19];
    const float* b_o      = (const float*)d_in[20];
    float* out = (float*)d_out;

    // fp32 arena (total 295,530,016 <= proven ws floor).
    // Depth-loop regions: P@0, S@157287600, MA@235931408, TH@275254208.
    // Scan overlays: gi_f@0, gi_b@117964800, msgx/AH in MA, h0 + WQ_f/b in TH.
    const size_t NEED = 295530016;
    if (ws_size < NEED) return;

    char* b = (char*)d_ws;
    float* P   = (float*)b;
    float* S   = (float*)(b + 157287600);
    float* MA  = (float*)(b + 235931408);
    float* TH  = (float*)(b + 275254208);

    float* Pia  = P + (size_t)AA * HH;        // ia_rc [A,300]
    float* giF  = (float*)b;                  // [ML,900]
    float* giB  = (float*)(b + 117964800);    // [ML,900]
    float* MSGX = MA;                         // [ML,300] (MA dead post-node)
    float* AH   = MA;                         // atomhid [ML,300]
    float* H0   = TH;                         // [M,300]
    float* WQ_f = TH + 76800;                 // 270,000 floats
    float* WQ_b = TH + 346800;                // 270,000 floats

    dim3 blk(256);
    const int gA = cdiv((long)AA * HH, 256);
    dim3 gmA (cdiv(AA, 128),   cdiv(HH, 64));
    dim3 gmB3(cdiv(BBND, 128), cdiv(HH, 64));
    dim3 gmB1(cdiv(BBND, 128), cdiv(150, 64));
    dim3 gmT (cdiv(AA, 128),   cdiv(150, 64));
    dim3 gmG (cdiv(MLR, 128),  cdiv(H3, 64));
    dim3 gmO (cdiv(MLR, 128),  cdiv(HH, 64));

    // 1. ma = input_atom ; 2. mb0 = input_bond -> P
    gemm_big<true, false, false><<<gmA, blk, 0, stream>>>(
        f_atoms, AFD, W_i_atom, AFD, nullptr, MA, AA, HH, AFD);
    gemm_big<true, false, false><<<gmB3, blk, 0, stream>>>(
        f_bonds, BFD, W_i_bond, BFD, nullptr, P, BBND, HH, BFD);

    // Depth loop
    const float* Wh[2] = { W_h0, W_h1 };
    for (int d = 0; d < 2; ++d) {
        const float* W = Wh[d];
        aggregate<true><<<gA, blk, 0, stream>>>(P, a2b, MA);
        // Vw_lo = (P @ W^T)[:, 0:150) -> S   (full-stripe, X staged once)
        vw_gemm<<<cdiv(BBND, 128), blk, 0, stream>>>(P, W, 0, S, 150, BBND);
        // Vw_hi = (P @ W^T)[:, 150:300) -> P[:, 0:150) in place
        vw_gemm<<<cdiv(BBND, 128), blk, 0, stream>>>(P, W, 150, P, 300, BBND);
        gemm_big<false, false, false><<<gmT, blk, 0, stream>>>(
            MA, HH, W + 150 * HH, HH, nullptr, TH, AA, 150, HH);
        bond_half<<<gmB1, blk, 0, stream>>>(
            f_bonds, W_i_bond, TH, P, 300, b2a, b2revb, P, 150, BBND);
        gemm_big<false, false, false><<<gmT, blk, 0, stream>>>(
            MA, HH, W, HH, nullptr, TH, AA, 150, HH);
        bond_half<<<gmB1, blk, 0, stream>>>(
            f_bonds, W_i_bond, TH, S, 150, b2a, b2revb, P, 0, BBND);
    }

    // Final aggregation -> S
    aggregate<false><<<gA, blk, 0, stream>>>(P, a2b, S);

    // ia recomputed -> Pia ; node -> P[0:A*300)
    gemm_big<true, false, false><<<gmA, blk, 0, stream>>>(
        f_atoms, AFD, W_i_atom, AFD, nullptr, Pia, AA, HH, AFD);
    gemm_big<false, false, false><<<gmA, blk, 0, stream>>>(
        S,   HH, W_lr,          H3, nullptr, P, AA, HH, HH);
    gemm_big<false, false, true><<<gmA, blk, 0, stream>>>(
        MA,  HH, W_lr + HH,     H3, nullptr, P, AA, HH, HH);
    gemm_big<false, false, true><<<gmA, blk, 0, stream>>>(
        Pia, HH, W_lr + 2 * HH, H3, nullptr, P, AA, HH, HH);

    // GRU prep: msgx -> MA region, h0 -> TH, WQ interleaved transposes -> TH
    msgx_kernel<<<cdiv((long)MLR * HH, 256), blk, 0, stream>>>(P, gru_bias, MSGX);
    h0_kernel<<<cdiv(MMOL * HH, 256), blk, 0, stream>>>(P, H0);
    transposeQ<<<cdiv(270000, 256), blk, 0, stream>>>(Whh_f, WQ_f);
    transposeQ<<<cdiv(270000, 256), blk, 0, stream>>>(Whh_b, WQ_b);

    // gi = msgx @ Wih^T + bih (both dirs; overwrites node/mb/agg — all dead)
    gemm_big<false, true, false><<<gmG, blk, 0, stream>>>(
        MSGX, HH, Wih_f, HH, bih_f, giF, MLR, H3, HH);
    gemm_big<false, true, false><<<gmG, blk, 0, stream>>>(
        MSGX, HH, Wih_b, HH, bih_b, giB, MLR, H3, HH);

    // Fused bidirectional scan (gout in-place into gi[t][0:300])
    gru_scan3<<<dim3(256), dim3(1024), 0, stream>>>(
        WQ_f, bhh_f, WQ_b, bhh_b, H0, giF, giB);

    // atom_hiddens = relu(gout_f@Wo_lo^T + gout_b@Wo_hi^T + b_o) -> AH
    gemm_big<false, false, false><<<gmO, blk, 0, stream>>>(
        giF, H3, W_o,      2 * HH, nullptr, AH, MLR, HH, HH);
    gemm_big<true, true, true><<<gmO, blk, 0, stream>>>(
        giB, H3, W_o + HH, 2 * HH, b_o,     AH, MLR, HH, HH);

    // mol_vecs -> out
    mean_kernel<<<cdiv(MMOL * HH, 256), blk, 0, stream>>>(AH, out);
}

// Round 14
// 5217.522 us; speedup vs baseline: 1.3478x; 1.0925x over previous
//
#include <hip/hip_runtime.h>
#include <math.h>

// Problem constants
#define HH   300
#define H3   900
#define MMOL 256
#define LATM 128
#define AA   32769        // 1 + 256*128
#define NBB  6
#define BBND 131073       // 1 + 4*256*128
#define AFD  133
#define BFD  147
#define MLR  (MMOL * LATM)   // 32768

static __device__ __forceinline__ float sigm(float x) { return 1.0f / (1.0f + expf(-x)); }

// ---------------------------------------------------------------------------
// Tiled fp32 GEMM, 128x64 tile, BK=16, 8x4 microtile, 256 threads.
// Register-prefetch, single LDS buffer (round-11 proven config).
// ---------------------------------------------------------------------------
template<bool RELU, bool BIAS, bool ACCUM>
__global__ __launch_bounds__(256)
void gemm_big(const float* __restrict__ X, int ldx, const float* __restrict__ W, int ldw,
              const float* __restrict__ Bias, float* __restrict__ C,
              int rows, int N, int K)
{
    __shared__ float Xs[16][132];
    __shared__ float Ws[16][68];
    const int row0 = blockIdx.x * 128;
    const int col0 = blockIdx.y * 64;
    const int tid  = threadIdx.x;
    const int tm   = (tid >> 4) * 8;
    const int tn   = (tid & 15) * 4;
    const bool xv  = ((ldx & 3) == 0);
    const bool wv  = ((ldw & 3) == 0);

    float px[2][4], pw[4];

    auto loadTile = [&](int k0) {
        const int rem = K - k0;
#pragma unroll
        for (int l = 0; l < 2; ++l) {
            int s = tid + l * 256;
            int r = s >> 2, kq = (s & 3) * 4;
            int gr = row0 + r;
            float v0 = 0, v1 = 0, v2 = 0, v3 = 0;
            if (gr < rows) {
                const float* xp = X + (long)gr * ldx + k0 + kq;
                if (xv && rem >= 16) {
                    float4 t4 = *(const float4*)xp;
                    v0 = t4.x; v1 = t4.y; v2 = t4.z; v3 = t4.w;
                } else {
                    if (kq + 0 < rem) v0 = xp[0];
                    if (kq + 1 < rem) v1 = xp[1];
                    if (kq + 2 < rem) v2 = xp[2];
                    if (kq + 3 < rem) v3 = xp[3];
                }
            }
            px[l][0] = v0; px[l][1] = v1; px[l][2] = v2; px[l][3] = v3;
        }
        {
            int r = tid >> 2, kq = (tid & 3) * 4;
            int gc = col0 + r;
            float v0 = 0, v1 = 0, v2 = 0, v3 = 0;
            if (gc < N) {
                const float* wp = W + (long)gc * ldw + k0 + kq;
                if (wv && rem >= 16) {
                    float4 t4 = *(const float4*)wp;
                    v0 = t4.x; v1 = t4.y; v2 = t4.z; v3 = t4.w;
                } else {
                    if (kq + 0 < rem) v0 = wp[0];
                    if (kq + 1 < rem) v1 = wp[1];
                    if (kq + 2 < rem) v2 = wp[2];
                    if (kq + 3 < rem) v3 = wp[3];
                }
            }
            pw[0] = v0; pw[1] = v1; pw[2] = v2; pw[3] = v3;
        }
    };
    auto commitTile = [&]() {
#pragma unroll
        for (int l = 0; l < 2; ++l) {
            int s = tid + l * 256;
            int r = s >> 2, kq = (s & 3) * 4;
            Xs[kq + 0][r] = px[l][0]; Xs[kq + 1][r] = px[l][1];
            Xs[kq + 2][r] = px[l][2]; Xs[kq + 3][r] = px[l][3];
        }
        {
            int r = tid >> 2, kq = (tid & 3) * 4;
            Ws[kq + 0][r] = pw[0]; Ws[kq + 1][r] = pw[1];
            Ws[kq + 2][r] = pw[2]; Ws[kq + 3][r] = pw[3];
        }
    };

    float acc[8][4];
#pragma unroll
    for (int i = 0; i < 8; ++i)
#pragma unroll
        for (int j = 0; j < 4; ++j) acc[i][j] = 0.0f;

    loadTile(0);
    for (int k0 = 0; k0 < K; k0 += 16) {
        commitTile();
        __syncthreads();
        if (k0 + 16 < K) loadTile(k0 + 16);
#pragma unroll
        for (int kk = 0; kk < 16; ++kk) {
            float4 xa = *(const float4*)&Xs[kk][tm];
            float4 xb = *(const float4*)&Xs[kk][tm + 4];
            float4 wq = *(const float4*)&Ws[kk][tn];
            float xr[8] = {xa.x, xa.y, xa.z, xa.w, xb.x, xb.y, xb.z, xb.w};
            float wr[4] = {wq.x, wq.y, wq.z, wq.w};
#pragma unroll
            for (int i = 0; i < 8; ++i)
#pragma unroll
                for (int j = 0; j < 4; ++j)
                    acc[i][j] += xr[i] * wr[j];
        }
        __syncthreads();
    }

#pragma unroll
    for (int i = 0; i < 8; ++i) {
        int gr = row0 + tm + i;
        if (gr >= rows) continue;
#pragma unroll
        for (int j = 0; j < 4; ++j) {
            int gc = col0 + tn + j;
            if (gc >= N) continue;
            float v = acc[i][j];
            if (BIAS)  v += Bias[gc];
            if (ACCUM) v += C[(long)gr * N + gc];
            if (RELU)  v = fmaxf(v, 0.0f);
            C[(long)gr * N + gc] = v;
        }
    }
}

// transposeQ: Whh[900][300] -> WQ[(k/4)][n][4]
__global__ void transposeQ(const float* __restrict__ in, float* __restrict__ out)
{
    long idx = (long)blockIdx.x * blockDim.x + threadIdx.x;
    if (idx >= 270000) return;
    int n = (int)(idx / 300), k = (int)(idx - (long)n * 300);
    out[(long)(k >> 2) * 3600 + n * 4 + (k & 3)] = in[idx];
}

// ---------------------------------------------------------------------------
// MFMA fp32-equivalent GEMM via 3-way bf16 split (6 products):
//   C[rows x 150] = X[rows x 300] @ Wb[0:150, 0:300]^T
// Block 256 thr = 4 waves; tile 64x64; K chunks of 32 (pad last).
// Validation target this round: the T-gemms only.
// ---------------------------------------------------------------------------
typedef __attribute__((ext_vector_type(8))) short bfrag;   // 8 bf16
typedef __attribute__((ext_vector_type(4))) float ffrag;   // 4 f32

static __device__ __forceinline__ unsigned short f2bf(float x) {
    unsigned u = __float_as_uint(x);
    u += 0x7FFF + ((u >> 16) & 1);
    return (unsigned short)(u >> 16);
}
static __device__ __forceinline__ float bf2f(unsigned short h) {
    return __uint_as_float(((unsigned)h) << 16);
}

__global__ __launch_bounds__(256)
void mfma_gemm150(const float* __restrict__ X, const float* __restrict__ Wb,
                  float* __restrict__ C, int ldc, int rows)
{
    __shared__ __align__(16) unsigned short Xp[3][64][40];
    __shared__ __align__(16) unsigned short Wp[3][64][40];
    const int tid  = threadIdx.x;
    const int lane = tid & 63;
    const int wv   = tid >> 6;           // 0..3
    const int row0 = blockIdx.x * 64;
    const int col0 = blockIdx.y * 64;
    const int wr   = (wv >> 1) * 32;
    const int wc   = (wv & 1) * 32;
    const int sr   = tid >> 2;           // staging row 0..63
    const int sk   = (tid & 3) * 8;      // staging k offset

    ffrag acc[2][2];
#pragma unroll
    for (int i = 0; i < 2; ++i)
#pragma unroll
        for (int j = 0; j < 2; ++j) acc[i][j] = (ffrag){0.0f, 0.0f, 0.0f, 0.0f};

    for (int k0 = 0; k0 < 300; k0 += 32) {
        // ---- stage X and W tiles as 3 bf16 planes ----
        {
            unsigned short h8[8], m8[8], l8[8];
            int gr = row0 + sr;
#pragma unroll
            for (int i = 0; i < 8; ++i) {
                int k = k0 + sk + i;
                float x = (gr < rows && k < 300) ? X[(long)gr * 300 + k] : 0.0f;
                unsigned short h = f2bf(x); float r1 = x - bf2f(h);
                unsigned short m = f2bf(r1); float r2 = r1 - bf2f(m);
                h8[i] = h; m8[i] = m; l8[i] = f2bf(r2);
            }
            *(bfrag*)&Xp[0][sr][sk] = *(bfrag*)h8;
            *(bfrag*)&Xp[1][sr][sk] = *(bfrag*)m8;
            *(bfrag*)&Xp[2][sr][sk] = *(bfrag*)l8;

            int wrow = col0 + sr;
#pragma unroll
            for (int i = 0; i < 8; ++i) {
                int k = k0 + sk + i;
                float x = (wrow < 150 && k < 300) ? Wb[(long)wrow * 300 + k] : 0.0f;
                unsigned short h = f2bf(x); float r1 = x - bf2f(h);
                unsigned short m = f2bf(r1); float r2 = r1 - bf2f(m);
                h8[i] = h; m8[i] = m; l8[i] = f2bf(r2);
            }
            *(bfrag*)&Wp[0][sr][sk] = *(bfrag*)h8;
            *(bfrag*)&Wp[1][sr][sk] = *(bfrag*)m8;
            *(bfrag*)&Wp[2][sr][sk] = *(bfrag*)l8;
        }
        __syncthreads();

        const int fr = lane & 15;
        const int kb = (lane >> 4) * 8;
        bfrag ax[3][2], bx[3][2];
#pragma unroll
        for (int s = 0; s < 3; ++s)
#pragma unroll
            for (int t2 = 0; t2 < 2; ++t2) {
                ax[s][t2] = *(const bfrag*)&Xp[s][wr + t2 * 16 + fr][kb];
                bx[s][t2] = *(const bfrag*)&Wp[s][wc + t2 * 16 + fr][kb];
            }

#pragma unroll
        for (int st = 0; st < 2; ++st)
#pragma unroll
            for (int ct = 0; ct < 2; ++ct) {
                ffrag a = acc[st][ct];
                a = __builtin_amdgcn_mfma_f32_16x16x32_bf16(ax[1][st], bx[1][ct], a, 0, 0, 0); // mM
                a = __builtin_amdgcn_mfma_f32_16x16x32_bf16(ax[0][st], bx[2][ct], a, 0, 0, 0); // hL
                a = __builtin_amdgcn_mfma_f32_16x16x32_bf16(ax[2][st], bx[0][ct], a, 0, 0, 0); // lH
                a = __builtin_amdgcn_mfma_f32_16x16x32_bf16(ax[0][st], bx[1][ct], a, 0, 0, 0); // hM
                a = __builtin_amdgcn_mfma_f32_16x16x32_bf16(ax[1][st], bx[0][ct], a, 0, 0, 0); // mH
                a = __builtin_amdgcn_mfma_f32_16x16x32_bf16(ax[0][st], bx[0][ct], a, 0, 0, 0); // hH
                acc[st][ct] = a;
            }
        __syncthreads();
    }

    // epilogue: C/D layout col=lane&15, row=(lane>>4)*4+reg [HW-verified]
    const int orow = (lane >> 4) * 4;
    const int ocol = lane & 15;
#pragma unroll
    for (int st = 0; st < 2; ++st)
#pragma unroll
        for (int ct = 0; ct < 2; ++ct)
#pragma unroll
            for (int rg = 0; rg < 4; ++rg) {
                int gr = row0 + wr + st * 16 + orow + rg;
                int gc = col0 + wc + ct * 16 + ocol;
                if (gr < rows && gc < 150) C[(long)gr * ldc + gc] = acc[st][ct][rg];
            }
}

// ---------------------------------------------------------------------------
// vw_hi_gemm: in-place staged GEMM (proven round-10/11 win, unchanged).
//   P[r, 0:150) = (P[r, 0:300) @ W^T)[:, 150:300)
// ---------------------------------------------------------------------------
__global__ __launch_bounds__(256)
void vw_hi_gemm(float* __restrict__ P, const float* __restrict__ W, int rows)
{
    __shared__ float Xs[16][132];
    __shared__ float Ws[16][192];
    const int row0 = blockIdx.x * 128;
    const int tid  = threadIdx.x;
    const int tm   = (tid >> 4) * 8;
    const int tn   = (tid & 15) * 4;

    float acc[8][12];
#pragma unroll
    for (int i = 0; i < 8; ++i)
#pragma unroll
        for (int j = 0; j < 12; ++j) acc[i][j] = 0.0f;

    for (int k0 = 0; k0 < 300; k0 += 16) {
        const int rem = 300 - k0;
#pragma unroll
        for (int l = 0; l < 2; ++l) {
            int s = tid + l * 256;
            int r = s >> 2, kq = (s & 3) * 4;
            int gr = row0 + r;
            float v0 = 0, v1 = 0, v2 = 0, v3 = 0;
            if (gr < rows) {
                const float* xp = P + (long)gr * 300 + k0 + kq;
                if (rem >= 16) {
                    float4 t4 = *(const float4*)xp;
                    v0 = t4.x; v1 = t4.y; v2 = t4.z; v3 = t4.w;
                } else {
                    if (kq + 0 < rem) v0 = xp[0];
                    if (kq + 1 < rem) v1 = xp[1];
                    if (kq + 2 < rem) v2 = xp[2];
                    if (kq + 3 < rem) v3 = xp[3];
                }
            }
            Xs[kq + 0][r] = v0; Xs[kq + 1][r] = v1;
            Xs[kq + 2][r] = v2; Xs[kq + 3][r] = v3;
        }
        for (int s = tid; s < 600; s += 256) {
            int r = s >> 2, kq = (s & 3) * 4;
            const float* wp = W + (long)(150 + r) * 300 + k0 + kq;
            float v0 = 0, v1 = 0, v2 = 0, v3 = 0;
            if (rem >= 16) {
                float4 t4 = *(const float4*)wp;
                v0 = t4.x; v1 = t4.y; v2 = t4.z; v3 = t4.w;
            } else {
                if (kq + 0 < rem) v0 = wp[0];
                if (kq + 1 < rem) v1 = wp[1];
                if (kq + 2 < rem) v2 = wp[2];
                if (kq + 3 < rem) v3 = wp[3];
            }
            Ws[kq + 0][r] = v0; Ws[kq + 1][r] = v1;
            Ws[kq + 2][r] = v2; Ws[kq + 3][r] = v3;
        }
        __syncthreads();
#pragma unroll
        for (int kk = 0; kk < 16; ++kk) {
            float4 xa = *(const float4*)&Xs[kk][tm];
            float4 xb = *(const float4*)&Xs[kk][tm + 4];
            float4 w0 = *(const float4*)&Ws[kk][tn];
            float4 w1 = *(const float4*)&Ws[kk][tn + 64];
            float4 w2 = *(const float4*)&Ws[kk][tn + 128];
            float xr[8] = {xa.x, xa.y, xa.z, xa.w, xb.x, xb.y, xb.z, xb.w};
            float wr[12] = {w0.x, w0.y, w0.z, w0.w, w1.x, w1.y, w1.z, w1.w,
                            w2.x, w2.y, w2.z, w2.w};
#pragma unroll
            for (int i = 0; i < 8; ++i)
#pragma unroll
                for (int j = 0; j < 12; ++j)
                    acc[i][j] += xr[i] * wr[j];
        }
        __syncthreads();
    }

#pragma unroll
    for (int i = 0; i < 8; ++i) {
        int gr = row0 + tm + i;
        if (gr >= rows) continue;
#pragma unroll
        for (int c = 0; c < 3; ++c)
#pragma unroll
            for (int j = 0; j < 4; ++j) {
                int cn = tn + c * 64 + j;
                if (cn < 150) P[(long)gr * 300 + cn] = acc[i][c * 4 + j];
            }
    }
}

// ---------------------------------------------------------------------------
// Half-column bond update (128x64 tiles, K=147 recomputed input_bond)
// ---------------------------------------------------------------------------
__global__ __launch_bounds__(256)
void bond_half(const float* __restrict__ FB, const float* __restrict__ WiB,
               const float* __restrict__ Th, const float* __restrict__ Vsrc, int vstride,
               const int* __restrict__ b2a, const int* __restrict__ b2revb,
               float* __restrict__ P, int c0, int rows)
{
    __shared__ float Xs[16][132];
    __shared__ float Ws[16][68];
    __shared__ int ra[128], rb[128];
    const int row0 = blockIdx.x * 128;
    const int col0 = blockIdx.y * 64;
    const int tid  = threadIdx.x;

    if (tid < 128) {
        int gr = row0 + tid;
        ra[tid] = (gr < rows) ? b2a[gr] : 0;
    } else {
        int m = tid - 128;
        int gr = row0 + m;
        rb[m] = (gr < rows) ? b2revb[gr] : 0;
    }

    const int tm = (tid >> 4) * 8;
    const int tn = (tid & 15) * 4;
    float acc[8][4];
#pragma unroll
    for (int i = 0; i < 8; ++i)
#pragma unroll
        for (int j = 0; j < 4; ++j) acc[i][j] = 0.0f;

    for (int k0 = 0; k0 < BFD; k0 += 16) {
        const int rem = BFD - k0;
#pragma unroll
        for (int l = 0; l < 2; ++l) {
            int s = tid + l * 256;
            int r = s >> 2, kq = (s & 3) * 4;
            int gr = row0 + r;
            float v0 = 0, v1 = 0, v2 = 0, v3 = 0;
            if (gr < rows) {
                const float* xp = FB + (long)gr * BFD + k0 + kq;
                if (kq + 0 < rem) v0 = xp[0];
                if (kq + 1 < rem) v1 = xp[1];
                if (kq + 2 < rem) v2 = xp[2];
                if (kq + 3 < rem) v3 = xp[3];
            }
            Xs[kq + 0][r] = v0; Xs[kq + 1][r] = v1;
            Xs[kq + 2][r] = v2; Xs[kq + 3][r] = v3;
        }
        {
            int r = tid >> 2, kq = (tid & 3) * 4;
            int gc = col0 + r;
            float v0 = 0, v1 = 0, v2 = 0, v3 = 0;
            if (gc < 150) {
                const float* wp = WiB + (long)(c0 + gc) * BFD + k0 + kq;
                if (kq + 0 < rem) v0 = wp[0];
                if (kq + 1 < rem) v1 = wp[1];
                if (kq + 2 < rem) v2 = wp[2];
                if (kq + 3 < rem) v3 = wp[3];
            }
            Ws[kq + 0][r] = v0; Ws[kq + 1][r] = v1;
            Ws[kq + 2][r] = v2; Ws[kq + 3][r] = v3;
        }
        __syncthreads();
#pragma unroll
        for (int kk = 0; kk < 16; ++kk) {
            float4 xa = *(const float4*)&Xs[kk][tm];
            float4 xb = *(const float4*)&Xs[kk][tm + 4];
            float4 wq = *(const float4*)&Ws[kk][tn];
            float xr[8] = {xa.x, xa.y, xa.z, xa.w, xb.x, xb.y, xb.z, xb.w};
            float wr[4] = {wq.x, wq.y, wq.z, wq.w};
#pragma unroll
            for (int i = 0; i < 8; ++i)
#pragma unroll
                for (int j = 0; j < 4; ++j)
                    acc[i][j] += xr[i] * wr[j];
        }
        __syncthreads();
    }

#pragma unroll
    for (int i = 0; i < 8; ++i) {
        int gr = row0 + tm + i;
        if (gr >= rows) continue;
        int a  = ra[tm + i];
        int rv = rb[tm + i];
#pragma unroll
        for (int j = 0; j < 4; ++j) {
            int cn = col0 + tn + j;
            if (cn >= 150) continue;
            float ib = fmaxf(acc[i][j], 0.0f);
            float v  = ib + Th[(long)a * 150 + cn] - Vsrc[(long)rv * vstride + cn];
            P[(long)gr * 300 + c0 + cn] = fmaxf(v, 0.0f);
        }
    }
}

template<bool ADD>
__global__ void aggregate(const float* __restrict__ mb, const int* __restrict__ a2b,
                          float* __restrict__ dst)
{
    long idx = (long)blockIdx.x * blockDim.x + threadIdx.x;
    if (idx >= (long)AA * HH) return;
    int a = (int)(idx / HH);
    int h = (int)(idx - (long)a * HH);
    const int* nb = a2b + (long)a * NBB;
    float s = 0.0f, mx = -INFINITY;
#pragma unroll
    for (int i = 0; i < NBB; ++i) {
        float v = mb[(long)nb[i] * HH + h];
        s += v;
        mx = fmaxf(mx, v);
    }
    float r = s * mx;
    if (ADD) r += dst[idx];
    dst[idx] = r;
}

__global__ void msgx_kernel(const float* __restrict__ node, const float* __restrict__ gbias,
                            float* __restrict__ msgx)
{
    long idx = (long)blockIdx.x * blockDim.x + threadIdx.x;
    if (idx >= (long)MLR * HH) return;
    int h = (int)(idx % HH);
    msgx[idx] = fmaxf(node[idx + HH] + gbias[h], 0.0f);
}

__global__ void h0_kernel(const float* __restrict__ node, float* __restrict__ hf)
{
    int idx = blockIdx.x * blockDim.x + threadIdx.x;
    if (idx >= MMOL * HH) return;
    int m = idx / HH;
    int h = idx - m * HH;
    long base = (long)(1 + m * LATM) * HH + h;
    float mx = -INFINITY;
    for (int t = 0; t < LATM; ++t) mx = fmaxf(mx, node[base + (long)t * HH]);
    hf[idx] = mx;
}

// ---------------------------------------------------------------------------
// GRU scan v3q (proven): 256 blocks, 2 mols, XCD-pinned dirs, WQ interleaved
// weights. gout in-place into gi.
// ---------------------------------------------------------------------------
__global__ __launch_bounds__(1024)
void gru_scan3(const float* __restrict__ WQ_f, const float* __restrict__ bhh_f,
               const float* __restrict__ WQ_b, const float* __restrict__ bhh_b,
               const float* __restrict__ h0, float* __restrict__ gi_f,
               float* __restrict__ gi_b)
{
    const int bid  = blockIdx.x;
    const int xcd  = bid & 7;
    const int dir  = (xcd >= 4) ? 1 : 0;
    const int rank = (bid >> 3) * 4 + (xcd & 3);
    const int m0   = rank * 2;
    const float* WQ  = dir ? WQ_b  : WQ_f;
    const float* bhh = dir ? bhh_b : bhh_f;
    float*       gi  = dir ? gi_b  : gi_f;
    const int tid = threadIdx.x;

    __shared__ float hs[2][304];
    __shared__ float ghs[2][H3];

    float bb = (tid < H3) ? bhh[tid] : 0.0f;

    for (int i = tid; i < 150; i += 1024) {
        int mm = i / 75, q = (i - mm * 75) * 4;
        *(float4*)&hs[mm][q] = *(const float4*)&h0[(long)(m0 + mm) * HH + q];
    }
    __syncthreads();

    for (int s = 0; s < LATM; ++s) {
        const int t = dir ? (LATM - 1 - s) : s;

        if (tid < H3) {
            float a0 = 0.0f, a1 = 0.0f;
            const float* wq = WQ + (long)tid * 4;
#pragma unroll 4
            for (int k0 = 0; k0 < HH; k0 += 4) {
                float4 w = *(const float4*)wq;
                wq += 3600;
                float4 h0v = *(const float4*)&hs[0][k0];
                float4 h1v = *(const float4*)&hs[1][k0];
                a0 += h0v.x * w.x + h0v.y * w.y + h0v.z * w.z + h0v.w * w.w;
                a1 += h1v.x * w.x + h1v.y * w.y + h1v.z * w.z + h1v.w * w.w;
            }
            ghs[0][tid] = a0 + bb;
            ghs[1][tid] = a1 + bb;
        }
        __syncthreads();

        if (tid < 2 * HH) {
            int mm = tid / HH, hh = tid - mm * HH;
            long row = (long)(m0 + mm) * LATM + t;
            float* g = gi + row * H3;
            float ir = g[hh], iz = g[HH + hh], inn = g[2 * HH + hh];
            float r  = sigm(ir + ghs[mm][hh]);
            float z  = sigm(iz + ghs[mm][HH + hh]);
            float nn = tanhf(inn + r * ghs[mm][2 * HH + hh]);
            float hn = (1.0f - z) * nn + z * hs[mm][hh];
            hs[mm][hh] = hn;
            g[hh] = hn;
        }
        __syncthreads();
    }
}

__global__ void mean_kernel(const float* __restrict__ ah, float* __restrict__ out)
{
    int idx = blockIdx.x * blockDim.x + threadIdx.x;
    if (idx >= MMOL * HH) return;
    int m = idx / HH;
    int j = idx - m * HH;
    long base = (long)m * LATM * HH + j;
    float s = 0.0f;
    for (int t = 0; t < LATM; ++t) s += ah[base + (long)t * HH];
    out[idx] = s * (1.0f / LATM);
}

// ---------------------------------------------------------------------------
static inline int cdiv(long a, long b) { return (int)((a + b - 1) / b); }

extern "C" void kernel_launch(void* const* d_in, const int* in_sizes, int n_in,
                              void* d_out, int out_size, void* d_ws, size_t ws_size,
                              hipStream_t stream)
{
    const float* f_atoms  = (const float*)d_in[0];
    const float* f_bonds  = (const float*)d_in[1];
    const int*   a2b      = (const int*)d_in[2];
    const int*   b2a      = (const int*)d_in[3];
    const int*   b2revb   = (const int*)d_in[4];
    const float* W_i_atom = (const float*)d_in[5];
    const float* W_i_bond = (const float*)d_in[6];
    const float* W_h0     = (const float*)d_in[7];
    const float* W_h1     = (const float*)d_in[8];
    const float* W_lr     = (const float*)d_in[9];
    const float* gru_bias = (const float*)d_in[10];
    const float* Wih_f    = (const float*)d_in[11];
    const float* Whh_f    = (const float*)d_in[12];
    const float* bih_f    = (const float*)d_in[13];
    const float* bhh_f    = (const float*)d_in[14];
    const float* Wih_b    = (const float*)d_in[15];
    const float* Whh_b    = (const float*)d_in[16];
    const float* bih_b    = (const float*)d_in[17];
    const float* bhh_b    = (const float*)d_in[18];
    const float* W_o      = (const float*)d_in[19];
    const float* b_o      = (const float*)d_in[20];
    float* out = (float*)d_out;

    const size_t NEED = 295530016;
    if (ws_size < NEED) return;

    char* b = (char*)d_ws;
    float* P   = (float*)b;
    float* S   = (float*)(b + 157287600);
    float* MA  = (float*)(b + 235931408);
    float* TH  = (float*)(b + 275254208);

    float* Pia  = P + (size_t)AA * HH;        // ia_rc [A,300]
    float* giF  = (float*)b;                  // [ML,900]
    float* giB  = (float*)(b + 117964800);    // [ML,900]
    float* MSGX = MA;                         // [ML,300]
    float* AH   = MA;                         // atomhid [ML,300]
    float* H0   = TH;                         // [M,300]
    float* WQ_f = TH + 76800;                 // 270,000 floats
    float* WQ_b = TH + 346800;                // 270,000 floats

    dim3 blk(256);
    const int gA = cdiv((long)AA * HH, 256);
    dim3 gmA (cdiv(AA, 128),   cdiv(HH, 64));
    dim3 gmB3(cdiv(BBND, 128), cdiv(HH, 64));
    dim3 gmB1(cdiv(BBND, 128), cdiv(150, 64));
    dim3 gmTm(cdiv(AA, 64),    3);            // mfma T-gemm grid
    dim3 gmG (cdiv(MLR, 128),  cdiv(H3, 64));
    dim3 gmO (cdiv(MLR, 128),  cdiv(HH, 64));

    // 1. ma = input_atom ; 2. mb0 = input_bond -> P
    gemm_big<true, false, false><<<gmA, blk, 0, stream>>>(
        f_atoms, AFD, W_i_atom, AFD, nullptr, MA, AA, HH, AFD);
    gemm_big<true, false, false><<<gmB3, blk, 0, stream>>>(
        f_bonds, BFD, W_i_bond, BFD, nullptr, P, BBND, HH, BFD);

    // Depth loop (round-11 proven structure; T-gemms on MFMA for validation)
    const float* Wh[2] = { W_h0, W_h1 };
    for (int d = 0; d < 2; ++d) {
        const float* W = Wh[d];
        aggregate<true><<<gA, blk, 0, stream>>>(P, a2b, MA);
        gemm_big<false, false, false><<<gmB1, blk, 0, stream>>>(
            P, HH, W, HH, nullptr, S, BBND, 150, HH);
        vw_hi_gemm<<<cdiv(BBND, 128), blk, 0, stream>>>(P, W, BBND);
        mfma_gemm150<<<gmTm, blk, 0, stream>>>(MA, W + 150 * HH, TH, 150, AA);
        bond_half<<<gmB1, blk, 0, stream>>>(
            f_bonds, W_i_bond, TH, P, 300, b2a, b2revb, P, 150, BBND);
        mfma_gemm150<<<gmTm, blk, 0, stream>>>(MA, W, TH, 150, AA);
        bond_half<<<gmB1, blk, 0, stream>>>(
            f_bonds, W_i_bond, TH, S, 150, b2a, b2revb, P, 0, BBND);
    }

    // Final aggregation -> S
    aggregate<false><<<gA, blk, 0, stream>>>(P, a2b, S);

    // ia recomputed -> Pia ; node -> P[0:A*300)
    gemm_big<true, false, false><<<gmA, blk, 0, stream>>>(
        f_atoms, AFD, W_i_atom, AFD, nullptr, Pia, AA, HH, AFD);
    gemm_big<false, false, false><<<gmA, blk, 0, stream>>>(
        S,   HH, W_lr,          H3, nullptr, P, AA, HH, HH);
    gemm_big<false, false, true><<<gmA, blk, 0, stream>>>(
        MA,  HH, W_lr + HH,     H3, nullptr, P, AA, HH, HH);
    gemm_big<false, false, true><<<gmA, blk, 0, stream>>>(
        Pia, HH, W_lr + 2 * HH, H3, nullptr, P, AA, HH, HH);

    // GRU prep
    msgx_kernel<<<cdiv((long)MLR * HH, 256), blk, 0, stream>>>(P, gru_bias, MSGX);
    h0_kernel<<<cdiv(MMOL * HH, 256), blk, 0, stream>>>(P, H0);
    transposeQ<<<cdiv(270000, 256), blk, 0, stream>>>(Whh_f, WQ_f);
    transposeQ<<<cdiv(270000, 256), blk, 0, stream>>>(Whh_b, WQ_b);

    // gi = msgx @ Wih^T + bih
    gemm_big<false, true, false><<<gmG, blk, 0, stream>>>(
        MSGX, HH, Wih_f, HH, bih_f, giF, MLR, H3, HH);
    gemm_big<false, true, false><<<gmG, blk, 0, stream>>>(
        MSGX, HH, Wih_b, HH, bih_b, giB, MLR, H3, HH);

    // Fused bidirectional scan
    gru_scan3<<<dim3(256), dim3(1024), 0, stream>>>(
        WQ_f, bhh_f, WQ_b, bhh_b, H0, giF, giB);

    // atom_hiddens -> AH
    gemm_big<false, false, false><<<gmO, blk, 0, stream>>>(
        giF, H3, W_o,      2 * HH, nullptr, AH, MLR, HH, HH);
    gemm_big<true, true, true><<<gmO, blk, 0, stream>>>(
        giB, H3, W_o + HH, 2 * HH, b_o,     AH, MLR, HH, HH);

    // mol_vecs -> out
    mean_kernel<<<cdiv(MMOL * HH, 256), blk, 0, stream>>>(AH, out);
}